// Round 5
// baseline (447.620 us; speedup 1.0000x reference)
//
#include <hip/hip_runtime.h>

#define NROWS 500000
#define DD 128
#define NSTACK 12
#define BNEPS 1e-3f
#define NCOL 50
#define NTILES ((NROWS + 63) / 64)          // 7813 row-tiles of 64

typedef float  v2f    __attribute__((ext_vector_type(2)));
typedef float  v4f    __attribute__((ext_vector_type(4)));
typedef float  f32x4  __attribute__((ext_vector_type(4)));
typedef __bf16 bf16x8 __attribute__((ext_vector_type(8)));

__device__ __forceinline__ unsigned short f2bf_rn(float f) {
    unsigned u = __float_as_uint(f);
    return (unsigned short)((u + 0x7FFFu + ((u >> 16) & 1u)) >> 16);
}

// ================= K1: x @ W -> T' (tile-transposed fp32 scratch) ============
// Per block: 4 waves x 64-row tiles. B (128x64, cols 50..63 zero) staged once
// in LDS in MFMA fragment order. A loads double-buffered across kt.
// T' layout: [tile][c(64)][rr(64)] so K2's per-row read is wave-coalesced.
__global__ __launch_bounds__(256, 3) void gemm_kernel(
    const float* __restrict__ x,
    const float* __restrict__ w0,  const float* __restrict__ w1,
    const float* __restrict__ w2,  const float* __restrict__ w3,
    const float* __restrict__ w4,  const float* __restrict__ w5,
    const float* __restrict__ w6,  const float* __restrict__ w7,
    const float* __restrict__ w8,  const float* __restrict__ w9,
    const float* __restrict__ w10, const float* __restrict__ w11,
    const float* __restrict__ wf,
    float* __restrict__ T)
{
    __shared__ __align__(16) unsigned short bsw[4][4][64][8];  // [kt][nt][lane][j] 16 KB

    const int tid = threadIdx.x;
    const float* ws[NSTACK] = {w0,w1,w2,w3,w4,w5,w6,w7,w8,w9,w10,w11};

    for (int idx = tid; idx < 1024; idx += 256)
        ((f32x4*)&bsw[0][0][0][0])[idx] = (f32x4){0.f, 0.f, 0.f, 0.f};
    __syncthreads();

#pragma unroll
    for (int i = 0; i < NSTACK; ++i) {
        const float* wsi = ws[i];
        for (int e = tid; e < 512; e += 256) {       // e = 4k+u
            const int k = e >> 2, u = e & 3;
            const int n = 4 * i + u;
            const int kt = k >> 5, q = (k >> 3) & 3, j = k & 7;
            const int nt = n >> 4, lane = q * 16 + (n & 15);
            bsw[kt][nt][lane][j] = f2bf_rn(wsi[16 * i + e]);
        }
    }
    {
        const int e = tid;                            // e = 2k+u
        const int k = e >> 1, u = e & 1;
        const int n = 48 + u;
        const int kt = k >> 5, q = (k >> 3) & 3, j = k & 7;
        const int lane = q * 16 + (n & 15);
        bsw[kt][3][lane][j] = f2bf_rn(wf[96 + e]);
    }
    __syncthreads();

    const int lane = tid & 63;
    const int wv   = tid >> 6;
    const int tile = blockIdx.x * 4 + wv;
    const int rowbase = tile * 64;
    const int m = lane & 15;
    const int q = lane >> 4;

    const float* arow[4];
#pragma unroll
    for (int mt = 0; mt < 4; ++mt) {
        int r = rowbase + mt * 16 + m;
        if (r > NROWS - 1) r = NROWS - 1;             // tail clamp
        arow[mt] = x + (size_t)r * DD + q * 8;
    }

    f32x4 acc[4][4];
#pragma unroll
    for (int mt = 0; mt < 4; ++mt)
#pragma unroll
        for (int nt = 0; nt < 4; ++nt) acc[mt][nt] = (f32x4){0.f, 0.f, 0.f, 0.f};

    // A double-buffer across kt
    v4f A0[2][4], A1[2][4];
#pragma unroll
    for (int mt = 0; mt < 4; ++mt) {
        A0[0][mt] = *(const v4f*)(arow[mt]);
        A1[0][mt] = *(const v4f*)(arow[mt] + 4);
    }

#pragma unroll
    for (int kt = 0; kt < 4; ++kt) {
        const int cur = kt & 1, nxt = cur ^ 1;
        if (kt < 3) {
#pragma unroll
            for (int mt = 0; mt < 4; ++mt) {          // prefetch kt+1
                A0[nxt][mt] = *(const v4f*)(arow[mt] + (kt + 1) * 32);
                A1[nxt][mt] = *(const v4f*)(arow[mt] + (kt + 1) * 32 + 4);
            }
        }
        bf16x8 bfrag[4];
#pragma unroll
        for (int nt = 0; nt < 4; ++nt)
            bfrag[nt] = *(const bf16x8*)&bsw[kt][nt][lane][0];
#pragma unroll
        for (int mt = 0; mt < 4; ++mt) {
            union { unsigned short us[8]; bf16x8 bv; } au;
#pragma unroll
            for (int e = 0; e < 4; ++e) {
                au.us[e]     = f2bf_rn(A0[cur][mt][e]);
                au.us[4 + e] = f2bf_rn(A1[cur][mt][e]);
            }
#pragma unroll
            for (int nt = 0; nt < 4; ++nt)
                acc[mt][nt] = __builtin_amdgcn_mfma_f32_16x16x32_bf16(
                    au.bv, bfrag[nt], acc[mt][nt], 0, 0, 0);
        }
    }

    // Epilogue: T'[tile][c][rr], coalesced dwordx4 (4 consecutive rows per reg quad)
    float* tb = T + (size_t)tile * 4096;
#pragma unroll
    for (int nt = 0; nt < 4; ++nt) {
        const int c = nt * 16 + m;
        if (c < NCOL) {
#pragma unroll
            for (int mt = 0; mt < 4; ++mt)
                *(v4f*)(tb + c * 64 + mt * 16 + q * 4) = acc[mt][nt];
        }
    }
}

// ================= K2: recurrence + softmax ================================
// One thread per row; T' read is lane-coalesced; weights via uniform-index
// scalar loads (K$-resident, broadcast for free).
__global__ __launch_bounds__(256, 4) void recur_kernel(
    const float* __restrict__ T,
    const float* __restrict__ w0,  const float* __restrict__ w1,
    const float* __restrict__ w2,  const float* __restrict__ w3,
    const float* __restrict__ w4,  const float* __restrict__ w5,
    const float* __restrict__ w6,  const float* __restrict__ w7,
    const float* __restrict__ w8,  const float* __restrict__ w9,
    const float* __restrict__ w10, const float* __restrict__ w11,
    const float* __restrict__ gamma_, const float* __restrict__ beta_,
    const float* __restrict__ mean_,  const float* __restrict__ var_,
    const float* __restrict__ wf,     const float* __restrict__ bf,
    float* __restrict__ out)
{
    const int row = blockIdx.x * blockDim.x + threadIdx.x;
    if (row >= NROWS) return;

    const float* ws[NSTACK] = {w0,w1,w2,w3,w4,w5,w6,w7,w8,w9,w10,w11};

    const int tile = row >> 6, rr = row & 63;
    const float* tb = T + (size_t)tile * 4096 + rr;

    float Tv[NCOL];
#pragma unroll
    for (int c = 0; c < NCOL; ++c) Tv[c] = tb[c * 64];   // coalesced across lanes

    float y[NSTACK * 4];
#pragma unroll
    for (int i = 0; i < NSTACK; ++i) {
        float a0 = Tv[4 * i + 0], a1 = Tv[4 * i + 1];
        float a2 = Tv[4 * i + 2], a3 = Tv[4 * i + 3];
        const float* wsi = ws[i];
#pragma unroll
        for (int mr = 0; mr < 4 * i; ++mr) {             // uniform idx -> s_load
            const float hv = y[(i - 1 - (mr >> 2)) * 4 + (mr & 3)];
            a0 += hv * wsi[4 * mr + 0];
            a1 += hv * wsi[4 * mr + 1];
            a2 += hv * wsi[4 * mr + 2];
            a3 += hv * wsi[4 * mr + 3];
        }
#pragma unroll
        for (int u = 0; u < 4; ++u) {
            const float sc = gamma_[4 * i + u] * __frsqrt_rn(var_[4 * i + u] + BNEPS);
            const float sh = beta_[4 * i + u] - mean_[4 * i + u] * sc;
            const float a  = (u == 0 ? a0 : u == 1 ? a1 : u == 2 ? a2 : a3);
            const float v  = a * sc + sh;
            y[4 * i + u] = v > 0.f ? v : 0.f;
        }
    }

    float l0 = Tv[48] + bf[0];
    float l1 = Tv[49] + bf[1];
#pragma unroll
    for (int mr = 0; mr < 48; ++mr) {                    // uniform idx -> s_load
        const float hv = y[(11 - (mr >> 2)) * 4 + (mr & 3)];
        l0 += hv * wf[2 * mr + 0];
        l1 += hv * wf[2 * mr + 1];
    }

    const float mx = fmaxf(l0, l1);
    const float e0 = __expf(l0 - mx);
    const float e1 = __expf(l1 - mx);
    const float inv = 1.0f / (e0 + e1);
    *(v2f*)(out + (size_t)row * 2) = (v2f){e0 * inv, e1 * inv};
}

extern "C" void kernel_launch(void* const* d_in, const int* in_sizes, int n_in,
                              void* d_out, int out_size, void* d_ws, size_t ws_size,
                              hipStream_t stream) {
    const float* x   = (const float*)d_in[0];
    const float* w0  = (const float*)d_in[1];
    const float* w1  = (const float*)d_in[2];
    const float* w2  = (const float*)d_in[3];
    const float* w3  = (const float*)d_in[4];
    const float* w4  = (const float*)d_in[5];
    const float* w5  = (const float*)d_in[6];
    const float* w6  = (const float*)d_in[7];
    const float* w7  = (const float*)d_in[8];
    const float* w8  = (const float*)d_in[9];
    const float* w9  = (const float*)d_in[10];
    const float* w10 = (const float*)d_in[11];
    const float* w11 = (const float*)d_in[12];
    const float* gm  = (const float*)d_in[13];
    const float* bt  = (const float*)d_in[14];
    const float* mn  = (const float*)d_in[15];
    const float* vr  = (const float*)d_in[16];
    const float* wf  = (const float*)d_in[17];
    const float* bf  = (const float*)d_in[18];
    float* out = (float*)d_out;
    float* T   = (float*)d_ws;          // NTILES*4096 floats = ~128 MB

    {
        dim3 block(256);
        dim3 grid((NTILES + 3) / 4);    // 4 tiles (waves) per block
        hipLaunchKernelGGL(gemm_kernel, grid, block, 0, stream,
                           x, w0, w1, w2, w3, w4, w5, w6, w7, w8, w9, w10, w11,
                           wf, T);
    }
    {
        dim3 block(256);
        dim3 grid((NROWS + 255) / 256);
        hipLaunchKernelGGL(recur_kernel, grid, block, 0, stream,
                           T, w0, w1, w2, w3, w4, w5, w6, w7, w8, w9, w10, w11,
                           gm, bt, mn, vr, wf, bf, out);
    }
}

// Round 6
// 420.187 us; speedup vs baseline: 1.0653x; 1.0653x over previous
//
#include <hip/hip_runtime.h>

#define NROWS 500000
#define DD 128
#define NSTACK 12
#define BNEPS 1e-3f
#define NCOL 50
#define NTILES ((NROWS + 63) / 64)      // 7813 tiles of 64 rows
#define NBLOCKS 768                     // 3 blocks/CU persistent
#define TRS 50                          // transpose-chunk row stride (200B, 8B-aligned)

typedef float  v2f    __attribute__((ext_vector_type(2)));
typedef float  v4f    __attribute__((ext_vector_type(4)));
typedef float  f32x4  __attribute__((ext_vector_type(4)));
typedef __bf16 bf16x8 __attribute__((ext_vector_type(8)));

__device__ __forceinline__ unsigned short f2bf_rn(float f) {
    unsigned u = __float_as_uint(f);
    return (unsigned short)((u + 0x7FFFu + ((u >> 16) & 1u)) >> 16);
}

// ---- Pre-kernel: build bf16 fragment-ordered B image + folded BN params in d_ws ----
// gbsw layout: [kt][nt][lane][j] u16, 16 KB.  scsh: sc[48], sh[48], bf[2].
__global__ __launch_bounds__(256) void prep_kernel(
    const float* __restrict__ w0,  const float* __restrict__ w1,
    const float* __restrict__ w2,  const float* __restrict__ w3,
    const float* __restrict__ w4,  const float* __restrict__ w5,
    const float* __restrict__ w6,  const float* __restrict__ w7,
    const float* __restrict__ w8,  const float* __restrict__ w9,
    const float* __restrict__ w10, const float* __restrict__ w11,
    const float* __restrict__ gamma_, const float* __restrict__ beta_,
    const float* __restrict__ mean_,  const float* __restrict__ var_,
    const float* __restrict__ wf,
    unsigned short* __restrict__ gbsw, float* __restrict__ scsh)
{
    const int tid = threadIdx.x;
    const float* ws[NSTACK] = {w0,w1,w2,w3,w4,w5,w6,w7,w8,w9,w10,w11};

    for (int idx = tid; idx < 1024; idx += 256)
        ((f32x4*)gbsw)[idx] = (f32x4){0.f, 0.f, 0.f, 0.f};
    __syncthreads();

#pragma unroll
    for (int i = 0; i < NSTACK; ++i) {
        const float* wsi = ws[i];
        for (int e = tid; e < 512; e += 256) {      // e = 4k+u
            const int k = e >> 2, u = e & 3;
            const int n = 4 * i + u;
            const int kt = k >> 5, q = (k >> 3) & 3, j = k & 7;
            const int nt = n >> 4, lane = q * 16 + (n & 15);
            gbsw[((kt * 4 + nt) * 64 + lane) * 8 + j] = f2bf_rn(wsi[16 * i + e]);
        }
    }
    {
        const int e = tid;                           // e = 2k+u
        const int k = e >> 1, u = e & 1;
        const int n = 48 + u;
        const int kt = k >> 5, q = (k >> 3) & 3, j = k & 7;
        const int lane = q * 16 + (n & 15);
        gbsw[((kt * 4 + 3) * 64 + lane) * 8 + j] = f2bf_rn(wf[96 + e]);
    }
    if (tid < 48) {
        const float sc = gamma_[tid] * __frsqrt_rn(var_[tid] + BNEPS);
        scsh[tid]      = sc;
        scsh[48 + tid] = beta_[tid] - mean_[tid] * sc;
    }
}

// ---- Main kernel: persistent, barrier-free after initial B stage ----
__global__ __launch_bounds__(256, 3) void predict_kernel(
    const float* __restrict__ x,
    const unsigned short* __restrict__ gbsw,
    const float* __restrict__ scsh,
    const float* __restrict__ w0,  const float* __restrict__ w1,
    const float* __restrict__ w2,  const float* __restrict__ w3,
    const float* __restrict__ w4,  const float* __restrict__ w5,
    const float* __restrict__ w6,  const float* __restrict__ w7,
    const float* __restrict__ w8,  const float* __restrict__ w9,
    const float* __restrict__ w10, const float* __restrict__ w11,
    const float* __restrict__ wf,  const float* __restrict__ bf,
    float* __restrict__ out)
{
    __shared__ __align__(16) unsigned short bsw[4][4][64][8];  // 16 KB
    __shared__ __align__(16) float trow[4][32 * TRS];          // 25.6 KB, wave-private

    const int tid = threadIdx.x;
    for (int idx = tid; idx < 1024; idx += 256)                // coalesced 16 KB stage
        ((f32x4*)&bsw[0][0][0][0])[idx] = ((const f32x4*)gbsw)[idx];
    __syncthreads();                                           // the ONLY barrier

    const float* ws[NSTACK] = {w0,w1,w2,w3,w4,w5,w6,w7,w8,w9,w10,w11};
    const int lane = tid & 63;
    const int wv   = tid >> 6;
    const int m = lane & 15;
    const int q = lane >> 4;
    const int slots = NBLOCKS * 4;
    float* wtr = &trow[wv][0];

    for (int tile = blockIdx.x * 4 + wv; tile < NTILES; tile += slots) {
        const int rowbase = tile * 64;

        const float* arow[4];
#pragma unroll
        for (int mt = 0; mt < 4; ++mt) {
            int r = rowbase + mt * 16 + m;
            if (r > NROWS - 1) r = NROWS - 1;                  // tail clamp
            arow[mt] = x + (size_t)r * DD + q * 8;
        }

        f32x4 acc[4][4];
#pragma unroll
        for (int mt = 0; mt < 4; ++mt)
#pragma unroll
            for (int nt = 0; nt < 4; ++nt) acc[mt][nt] = (f32x4){0.f, 0.f, 0.f, 0.f};

#pragma unroll
        for (int kt = 0; kt < 4; ++kt) {
            bf16x8 bfrag[4];
#pragma unroll
            for (int nt = 0; nt < 4; ++nt)
                bfrag[nt] = *(const bf16x8*)&bsw[kt][nt][lane][0];
#pragma unroll
            for (int mt = 0; mt < 4; ++mt) {
                const v4f a0 = *(const v4f*)(arow[mt] + kt * 32);
                const v4f a1 = *(const v4f*)(arow[mt] + kt * 32 + 4);
                union { unsigned short us[8]; bf16x8 bv; } au;
#pragma unroll
                for (int e = 0; e < 4; ++e) {
                    au.us[e]     = f2bf_rn(a0[e]);
                    au.us[4 + e] = f2bf_rn(a1[e]);
                }
#pragma unroll
                for (int nt = 0; nt < 4; ++nt)
                    acc[mt][nt] = __builtin_amdgcn_mfma_f32_16x16x32_bf16(
                        au.bv, bfrag[nt], acc[mt][nt], 0, 0, 0);
            }
        }

        // ---- chunked wave-private transpose (no barriers; wave-ordered LDS) ----
        float T[NCOL];
        // chunk 0: rows 0..31 (mt 0,1)
#pragma unroll
        for (int mt = 0; mt < 2; ++mt)
#pragma unroll
            for (int nt = 0; nt < 4; ++nt) {
                const int c = nt * 16 + m;
                if (c < NCOL) {
#pragma unroll
                    for (int r = 0; r < 4; ++r)
                        wtr[(mt * 16 + q * 4 + r) * TRS + c] = acc[mt][nt][r];
                }
            }
        if (lane < 32) {
            const float* tb = wtr + lane * TRS;
#pragma unroll
            for (int j = 0; j < NCOL / 2; ++j) {
                const v2f t = *(const v2f*)(tb + 2 * j);
                T[2 * j] = t.x; T[2 * j + 1] = t.y;
            }
        }
        // chunk 1: rows 32..63 (mt 2,3)
#pragma unroll
        for (int mt = 2; mt < 4; ++mt)
#pragma unroll
            for (int nt = 0; nt < 4; ++nt) {
                const int c = nt * 16 + m;
                if (c < NCOL) {
#pragma unroll
                    for (int r = 0; r < 4; ++r)
                        wtr[((mt - 2) * 16 + q * 4 + r) * TRS + c] = acc[mt][nt][r];
                }
            }
        if (lane >= 32) {
            const float* tb = wtr + (lane - 32) * TRS;
#pragma unroll
            for (int j = 0; j < NCOL / 2; ++j) {
                const v2f t = *(const v2f*)(tb + 2 * j);
                T[2 * j] = t.x; T[2 * j + 1] = t.y;
            }
        }

        // ---- recurrence: weights + BN params via uniform s_load ----
        float y[NSTACK * 4];
#pragma unroll
        for (int i = 0; i < NSTACK; ++i) {
            float a0 = T[4 * i + 0], a1 = T[4 * i + 1];
            float a2 = T[4 * i + 2], a3 = T[4 * i + 3];
            const float* wsi = ws[i];
#pragma unroll
            for (int mr = 0; mr < 4 * i; ++mr) {
                const float hv = y[(i - 1 - (mr >> 2)) * 4 + (mr & 3)];
                a0 += hv * wsi[4 * mr + 0];
                a1 += hv * wsi[4 * mr + 1];
                a2 += hv * wsi[4 * mr + 2];
                a3 += hv * wsi[4 * mr + 3];
            }
#pragma unroll
            for (int u = 0; u < 4; ++u) {
                const float sc = scsh[4 * i + u];
                const float sh = scsh[48 + 4 * i + u];
                const float a  = (u == 0 ? a0 : u == 1 ? a1 : u == 2 ? a2 : a3);
                const float v  = a * sc + sh;
                y[4 * i + u] = v > 0.f ? v : 0.f;
            }
        }

        float l0 = T[48] + bf[0];
        float l1 = T[49] + bf[1];
#pragma unroll
        for (int mr = 0; mr < 48; ++mr) {
            const float hv = y[(11 - (mr >> 2)) * 4 + (mr & 3)];
            l0 += hv * wf[2 * mr + 0];
            l1 += hv * wf[2 * mr + 1];
        }

        const float mx = fmaxf(l0, l1);
        const float e0 = __expf(l0 - mx);
        const float e1 = __expf(l1 - mx);
        const float inv = 1.0f / (e0 + e1);

        const int row = rowbase + lane;
        if (row < NROWS)
            *(v2f*)(out + (size_t)row * 2) = (v2f){e0 * inv, e1 * inv};
    }
}

extern "C" void kernel_launch(void* const* d_in, const int* in_sizes, int n_in,
                              void* d_out, int out_size, void* d_ws, size_t ws_size,
                              hipStream_t stream) {
    const float* x   = (const float*)d_in[0];
    const float* w0  = (const float*)d_in[1];
    const float* w1  = (const float*)d_in[2];
    const float* w2  = (const float*)d_in[3];
    const float* w3  = (const float*)d_in[4];
    const float* w4  = (const float*)d_in[5];
    const float* w5  = (const float*)d_in[6];
    const float* w6  = (const float*)d_in[7];
    const float* w7  = (const float*)d_in[8];
    const float* w8  = (const float*)d_in[9];
    const float* w9  = (const float*)d_in[10];
    const float* w10 = (const float*)d_in[11];
    const float* w11 = (const float*)d_in[12];
    const float* gm  = (const float*)d_in[13];
    const float* bt  = (const float*)d_in[14];
    const float* mn  = (const float*)d_in[15];
    const float* vr  = (const float*)d_in[16];
    const float* wf  = (const float*)d_in[17];
    const float* bf  = (const float*)d_in[18];
    float* out = (float*)d_out;

    unsigned short* gbsw = (unsigned short*)d_ws;              // 16 KB
    float*          scsh = (float*)((char*)d_ws + 16384);      // 98 floats

    hipLaunchKernelGGL(prep_kernel, dim3(1), dim3(256), 0, stream,
                       w0, w1, w2, w3, w4, w5, w6, w7, w8, w9, w10, w11,
                       gm, bt, mn, vr, wf, gbsw, scsh);

    hipLaunchKernelGGL(predict_kernel, dim3(NBLOCKS), dim3(256), 0, stream,
                       x, gbsw, scsh,
                       w0, w1, w2, w3, w4, w5, w6, w7, w8, w9, w10, w11,
                       wf, bf, out);
}